// Round 8
// baseline (426.265 us; speedup 1.0000x reference)
//
#include <hip/hip_runtime.h>
#include <hip/hip_bf16.h>
#include <hip/hip_fp16.h>

#define N_NODES 50000
#define N_EDGES 800000
#define IN_F 128
#define OUT_F 32
#define HEADS 4
#define EDGE_F 32
#define HF 128          // HEADS*OUT_F
#define SB 256          // scan block size
#define NBLK ((N_NODES + SB - 1) / SB)   // 196 scan blocks
#define NODE_BLKS ((N_NODES + 63) / 64)  // 782
#define CNT_BLKS ((N_EDGES / 4 + 255) / 256)  // 782

typedef __attribute__((ext_vector_type(8))) short short8_t;  // 8 bf16 (4 VGPRs)
typedef __attribute__((ext_vector_type(4))) float f32x4;

__device__ __forceinline__ unsigned short f2bf(float x) {
    unsigned int u = __float_as_uint(x);
    unsigned int r = (u + 0x7FFF + ((u >> 16) & 1)) >> 16;   // RNE
    return (unsigned short)r;
}
__device__ __forceinline__ float bf2f(unsigned short b) {
    return __uint_as_float(((unsigned int)b) << 16);
}

// ---- fused prep: blocks 0-7 = W->bf16 transpose+swizzle; block 8 = w_eff/b_eff
__global__ __launch_bounds__(256) void prep_kernel(
        const float* __restrict__ W, const float* __restrict__ eW,
        const float* __restrict__ eb, const float* __restrict__ a,
        unsigned short* __restrict__ W_T,
        float* __restrict__ w_eff, float* __restrict__ b_eff) {
    int t = threadIdx.x;
    if (blockIdx.x < 8) {
        int g = blockIdx.x * 256 + t;            // 2048 = 128 n * 16 chunks
        int n = g >> 4, c = g & 15;
        unsigned short w8[8];
        #pragma unroll
        for (int q = 0; q < 8; ++q)
            w8[q] = f2bf(W[(size_t)(8 * c + q) * 128 + n]);
        *(uint4*)&W_T[n * 128 + ((c ^ (n & 7)) << 3)] = *(uint4*)w8;
    } else {
        if (t < 128) {
            int k = t >> 2, h = t & 3;
            float s = 0.f;
            #pragma unroll
            for (int f = 0; f < EDGE_F; ++f)
                s = fmaf(eW[k * HF + h * OUT_F + f], a[h * 96 + 2 * OUT_F + f], s);
            w_eff[k * 4 + h] = s;
        } else if (t < 132) {
            int h = t - 128;
            float s = 0.f;
            #pragma unroll
            for (int f = 0; f < EDGE_F; ++f)
                s = fmaf(eb[h * OUT_F + f], a[h * 96 + 2 * OUT_F + f], s);
            b_eff[h] = s;
        }
    }
}

// ---- grid-union: blocks [0,782) = MFMA node body; [782,1564) = count body
// count (~10us, HBM+atomic-bound) hides under node (~45us, MFMA/LDS-bound).
__global__ __launch_bounds__(256) void node_count_kernel(
        const float* __restrict__ h, const unsigned short* __restrict__ W_T,
        const float* __restrict__ a,
        __hip_bfloat16* __restrict__ ht_bf,
        float* __restrict__ alpha_i, float* __restrict__ alpha_j,
        const int* __restrict__ row, int* __restrict__ deg,
        int* __restrict__ rank) {
    __shared__ __align__(16) unsigned short Wl[128 * 128];   // 32 KB swizzled [n][k]
    __shared__ __align__(16) unsigned short Hhi[64 * 128];   // 16 KB swizzled [row][k]
    __shared__ __align__(16) unsigned short Hlo[64 * 128];   // 16 KB
    int t = threadIdx.x;
    if (blockIdx.x >= NODE_BLKS) {
        // ---------------- count body ----------------
        int i = (blockIdx.x - NODE_BLKS) * 256 + t;   // over N_EDGES/4
        if (i < N_EDGES / 4) {
            int4 r4 = ((const int4*)row)[i];
            int4 k4;
            k4.x = atomicAdd(&deg[r4.x], 1);
            k4.y = atomicAdd(&deg[r4.y], 1);
            k4.z = atomicAdd(&deg[r4.z], 1);
            k4.w = atomicAdd(&deg[r4.w], 1);
            ((int4*)rank)[i] = k4;                    // coalesced 16B write
        }
        return;
    }
    // ---------------- node body ----------------
    int lane = t & 63, wave = t >> 6;
    int nb = blockIdx.x * 64;
    {   // copy pre-swizzled W (32 KB): linear b128, even 8-way = floor
        const uint4* src = (const uint4*)W_T;
        uint4* dst = (uint4*)Wl;
        #pragma unroll
        for (int u = 0; u < 8; ++u) dst[t + u * 256] = src[t + u * 256];
    }
    // stage 64 h rows: coalesced float4 global, split hi/lo, swizzled LDS write
    #pragma unroll
    for (int u = 0; u < 8; ++u) {
        int f = u * 256 + t;
        int r_ = f >> 5, q = f & 31;             // q: float4 within row (k=4q..4q+3)
        int gn = nb + r_; if (gn > N_NODES - 1) gn = N_NODES - 1;
        float4 v = ((const float4*)h)[(size_t)gn * 32 + q];
        unsigned short hi[4], lo[4];
        #pragma unroll
        for (int x = 0; x < 4; ++x) {
            float xv = (&v.x)[x];
            unsigned short hb = f2bf(xv);
            hi[x] = hb;
            lo[x] = f2bf(xv - bf2f(hb));
        }
        int c = q >> 1, half = q & 1;
        int off = r_ * 128 + ((c ^ (r_ & 7)) << 3) + half * 4;
        *(uint2*)&Hhi[off] = *(uint2*)hi;
        *(uint2*)&Hlo[off] = *(uint2*)lo;
    }
    __syncthreads();
    int n0 = nb + wave * 16;
    if (n0 >= N_NODES) return;                   // tail block: waves 1-3 idle
    int r = lane & 15, g = lane >> 4;
    short8_t ahi[4], alo[4];
    #pragma unroll
    for (int k = 0; k < 4; ++k) {
        int c = k * 4 + g;
        int off = (wave * 16 + r) * 128 + ((c ^ (r & 7)) << 3);
        ahi[k] = *(const short8_t*)&Hhi[off];
        alo[k] = *(const short8_t*)&Hlo[off];
    }
    f32x4 acc[8];
    #pragma unroll
    for (int i = 0; i < 8; ++i) acc[i] = (f32x4){0.f, 0.f, 0.f, 0.f};
    #pragma unroll
    for (int tt = 0; tt < 8; ++tt) {             // 8 col-tiles of 16
        int n = tt * 16 + r;
        #pragma unroll
        for (int k = 0; k < 4; ++k) {
            int c = k * 4 + g;
            short8_t b = *(const short8_t*)&Wl[n * 128 + ((c ^ (n & 7)) << 3)];
            acc[tt] = __builtin_amdgcn_mfma_f32_16x16x32_bf16(ahi[k], b, acc[tt], 0, 0, 0);
            acc[tt] = __builtin_amdgcn_mfma_f32_16x16x32_bf16(alo[k], b, acc[tt], 0, 0, 0);
        }
    }
    // D layout: row = 4g + reg, col = 16tt + r
    #pragma unroll
    for (int tt = 0; tt < 8; ++tt)
        #pragma unroll
        for (int reg = 0; reg < 4; ++reg) {
            int rowg = n0 + 4 * g + reg;
            ((unsigned short*)ht_bf)[(size_t)rowg * 128 + tt * 16 + r] = f2bf(acc[tt][reg]);
        }
    float pi[4][4], pj[4][4];                    // [head][reg]
    #pragma unroll
    for (int hh = 0; hh < 4; ++hh) {
        float ai0 = a[hh * 96 + r],      ai1 = a[hh * 96 + 16 + r];
        float aj0 = a[hh * 96 + 32 + r], aj1 = a[hh * 96 + 48 + r];
        #pragma unroll
        for (int reg = 0; reg < 4; ++reg) {
            float v0 = acc[2 * hh][reg], v1 = acc[2 * hh + 1][reg];
            pi[hh][reg] = fmaf(v0, ai0, v1 * ai1);
            pj[hh][reg] = fmaf(v0, aj0, v1 * aj1);
        }
    }
    #pragma unroll
    for (int hh = 0; hh < 4; ++hh)
        #pragma unroll
        for (int reg = 0; reg < 4; ++reg) {
            float vi = pi[hh][reg], vj = pj[hh][reg];
            #pragma unroll
            for (int s = 1; s < 16; s <<= 1) {   // reduce over the 16 cols (lanes r)
                vi += __shfl_xor(vi, s, 64);
                vj += __shfl_xor(vj, s, 64);
            }
            pi[hh][reg] = vi; pj[hh][reg] = vj;
        }
    if (r == 0) {                                // 4 lanes/wave store 32 scalars each
        #pragma unroll
        for (int hh = 0; hh < 4; ++hh)
            #pragma unroll
            for (int reg = 0; reg < 4; ++reg) {
                int rowg = n0 + 4 * g + reg;
                alpha_i[rowg * 4 + hh] = pi[hh][reg];
                alpha_j[rowg * 4 + hh] = pj[hh][reg];
            }
    }
}

// ---- hierarchical exclusive scan ----------------------------------------
__device__ __forceinline__ int block_incl_scan(int v, int lane, int wid, int* wsum) {
    int x = v;
    #pragma unroll
    for (int s = 1; s < 64; s <<= 1) {
        int y = __shfl_up(x, s, 64);
        if (lane >= s) x += y;
    }
    if (lane == 63) wsum[wid] = x;
    __syncthreads();
    int add = 0;
    #pragma unroll
    for (int w = 0; w < 4; ++w) add += (w < wid) ? wsum[w] : 0;
    return x + add;            // block-level inclusive scan of v
}

__global__ __launch_bounds__(SB) void scan1_kernel(const int* __restrict__ deg,
                                                   int* __restrict__ row_off,
                                                   int* __restrict__ blk_sums) {
    __shared__ int wsum[4];
    int i = blockIdx.x * SB + threadIdx.x;
    int v = (i < N_NODES) ? deg[i] : 0;
    int incl = block_incl_scan(v, threadIdx.x & 63, threadIdx.x >> 6, wsum);
    if (i < N_NODES) row_off[i] = incl - v;              // local exclusive
    if (threadIdx.x == SB - 1) blk_sums[blockIdx.x] = incl;
}

__global__ __launch_bounds__(SB) void scan2_kernel(int* __restrict__ blk_sums,
                                                   int* __restrict__ blk_off,
                                                   int* __restrict__ row_off) {
    __shared__ int wsum[4];
    int t = threadIdx.x;
    int v = (t < NBLK) ? blk_sums[t] : 0;
    int incl = block_incl_scan(v, t & 63, t >> 6, wsum);
    if (t < NBLK) blk_off[t] = incl - v;                 // exclusive block offset
    if (t == SB - 1) row_off[N_NODES] = incl;            // grand total (== N_EDGES)
}

// scan3: finalize row_off AND build packed node record
// nrec[n] = 32B {alpha_i[0..3] fp32, row_off as-int, pad3} -> one gather line
__global__ __launch_bounds__(SB) void scan3_kernel(const int* __restrict__ blk_off,
                                                   int* __restrict__ row_off,
                                                   const float* __restrict__ alpha_i,
                                                   float4* __restrict__ nrec) {
    int i = blockIdx.x * SB + threadIdx.x;
    if (i < N_NODES) {
        int v = row_off[i] + blk_off[blockIdx.x];
        row_off[i] = v;
        float4 ai = *(const float4*)(alpha_i + (size_t)i * 4);
        nrec[(size_t)i * 2] = ai;
        float4 m;
        m.x = __int_as_float(v); m.y = 0.f; m.z = 0.f; m.w = 0.f;
        nrec[(size_t)i * 2 + 1] = m;
    }
}

// ---- unified edge kernel (R3 structure + nrec packed gather) ------------
__global__ __launch_bounds__(256) void edge_kernel(
        const int* __restrict__ row, const int* __restrict__ col,
        const int* __restrict__ rank,
        const float* __restrict__ ea,
        const float* __restrict__ w_eff, const float* __restrict__ b_eff,
        const float4* __restrict__ nrec, const float* __restrict__ alpha_j,
        uint4* __restrict__ rec, float4* __restrict__ att_ex) {
    __shared__ __align__(16) float eas[256 * 36];  // 36 KB, stride 36 floats
    __shared__ float wsd[128];
    __shared__ float bs[4];
    int t = threadIdx.x;
    if (t < 128) wsd[t] = w_eff[t];
    if (t < 4) bs[t] = b_eff[t];
    int e0 = blockIdx.x * 256;
    {   // coalesced stage: 2048 float4 = 256 edges x 128B
        const float4* src = (const float4*)ea + (size_t)e0 * 8;
        #pragma unroll
        for (int u = 0; u < 8; ++u) {
            int f = u * 256 + t;
            int el = f >> 3, j = f & 7;
            *(float4*)&eas[el * 36 + 4 * j] = src[f];
        }
    }
    __syncthreads();
    int e = e0 + t;
    float4 ev[8];
    #pragma unroll
    for (int i = 0; i < 8; ++i) ev[i] = *(const float4*)&eas[t * 36 + 4 * i];
    int r = row[e], c = col[e];
    int rk = rank[e];
    f32x4 ai = ((const f32x4*)nrec)[(size_t)r * 2];
    int ro = ((const int*)nrec)[(size_t)r * 8 + 4];   // same 32B line as ai
    f32x4 aj = *(const f32x4*)(alpha_j + (size_t)c * 4);
    float s0 = bs[0], s1 = bs[1], s2 = bs[2], s3 = bs[3];
    #pragma unroll
    for (int i = 0; i < 8; ++i) {
        #pragma unroll
        for (int kk = 0; kk < 4; ++kk) {
            float x = (&ev[i].x)[kk];
            float4 w4 = *(const float4*)&wsd[(i * 4 + kk) * 4];  // uniform -> broadcast
            s0 = fmaf(x, w4.x, s0);
            s1 = fmaf(x, w4.y, s1);
            s2 = fmaf(x, w4.z, s2);
            s3 = fmaf(x, w4.w, s3);
        }
    }
    float e0v = s0 + ai[0] + aj[0];
    float e1v = s1 + ai[1] + aj[1];
    float e2v = s2 + ai[2] + aj[2];
    float e3v = s3 + ai[3] + aj[3];
    e0v = e0v > 0.f ? e0v : 0.2f * e0v;           // leaky_relu(0.2)
    e1v = e1v > 0.f ? e1v : 0.2f * e1v;
    e2v = e2v > 0.f ? e2v : 0.2f * e2v;
    e3v = e3v > 0.f ? e3v : 0.2f * e3v;
    float x0 = __expf(e0v), x1 = __expf(e1v), x2 = __expf(e2v), x3 = __expf(e3v);
    att_ex[e] = make_float4(x0, x1, x2, x3);      // coalesced; normalized later
    __half2 p01 = __floats2half2_rn(x0, x1);
    __half2 p23 = __floats2half2_rn(x2, x3);
    uint4 o;
    o.x = *reinterpret_cast<unsigned int*>(&p01);
    o.y = *reinterpret_cast<unsigned int*>(&p23);
    o.z = (unsigned int)c;
    o.w = 0u;
    rec[ro + rk] = o;                             // single scattered 16B store
}

// ---- per-node aggregation: one wave per node, unroll-8 gather MLP -------
__global__ __launch_bounds__(256) void agg_kernel(
        const int* __restrict__ row_off, const uint4* __restrict__ rec,
        const __hip_bfloat16* __restrict__ ht_bf,
        float* __restrict__ hout, float* __restrict__ rden_buf) {
    int wave = threadIdx.x >> 6;
    int lane = threadIdx.x & 63;
    int n = blockIdx.x * 4 + wave;
    if (n >= N_NODES) return;
    int beg = row_off[n], end = row_off[n + 1];
    int h2 = lane >> 4;                            // head of cols 2L,2L+1
    int sh = (h2 & 1) * 16;                        // half-select within dword
    float2 acc0 = {0.f, 0.f}, acc1 = {0.f, 0.f};
    float den0 = 0.f, den1 = 0.f;
    int p = beg;
    for (; p + 7 < end; p += 8) {                  // unroll x8: 8 gathers in flight
        uint4 rr[8];
        #pragma unroll
        for (int u = 0; u < 8; ++u) rr[u] = rec[p + u];
        float ex[8];
        #pragma unroll
        for (int u = 0; u < 8; ++u) {
            unsigned int w = (h2 & 2) ? rr[u].y : rr[u].x;
            ex[u] = __half2float(__ushort_as_half((unsigned short)(w >> sh)));
        }
        float2 hv[8];
        #pragma unroll
        for (int u = 0; u < 8; ++u)
            hv[u] = __bfloat1622float2(
                *(const __hip_bfloat162*)(ht_bf + (size_t)rr[u].z * HF + 2 * lane));
        #pragma unroll
        for (int u = 0; u < 8; u += 2) {
            acc0.x = fmaf(ex[u], hv[u].x, acc0.x);
            acc0.y = fmaf(ex[u], hv[u].y, acc0.y);
            acc1.x = fmaf(ex[u + 1], hv[u + 1].x, acc1.x);
            acc1.y = fmaf(ex[u + 1], hv[u + 1].y, acc1.y);
            den0 += ex[u]; den1 += ex[u + 1];
        }
    }
    for (; p < end; ++p) {
        uint4 rA = rec[p];
        unsigned int wA = (h2 & 2) ? rA.y : rA.x;
        float exA = __half2float(__ushort_as_half((unsigned short)(wA >> sh)));
        float2 hvA = __bfloat1622float2(
            *(const __hip_bfloat162*)(ht_bf + (size_t)rA.z * HF + 2 * lane));
        acc0.x = fmaf(exA, hvA.x, acc0.x); acc0.y = fmaf(exA, hvA.y, acc0.y);
        den0 += exA;
    }
    float den = den0 + den1;
    float rden = 1.0f / (den + 1e-8f);
    float ox = (acc0.x + acc1.x) * rden, oy = (acc0.y + acc1.y) * rden;
    ox = ox > 0.f ? ox : expm1f(ox);               // fused ELU
    oy = oy > 0.f ? oy : expm1f(oy);
    float2 o = {ox, oy};
    ((float2*)(hout + (size_t)n * HF))[lane] = o;
    if ((lane & 15) == 0)                          // 4 lanes: rden per head, 16B line
        rden_buf[n * 4 + h2] = rden;
}

// ---- e-order att normalization: coalesced RMW + tiny rden gather --------
__global__ __launch_bounds__(256) void norm_kernel(const int* __restrict__ row,
                                                   const float* __restrict__ rden_buf,
                                                   float* __restrict__ att) {
    int e = blockIdx.x * 256 + threadIdx.x;        // 800000 = 3125*256 exact
    float4 ex = ((const float4*)att)[e];
    int r = row[e];
    float4 rd = *(const float4*)(rden_buf + (size_t)r * 4);
    ex.x *= rd.x; ex.y *= rd.y; ex.z *= rd.z; ex.w *= rd.w;
    ((float4*)att)[e] = ex;
}

extern "C" void kernel_launch(void* const* d_in, const int* in_sizes, int n_in,
                              void* d_out, int out_size, void* d_ws, size_t ws_size,
                              hipStream_t stream) {
    const float* h  = (const float*)d_in[0];
    const int*   ei = (const int*)  d_in[1];
    const float* ea = (const float*)d_in[2];
    const float* W  = (const float*)d_in[3];
    const float* a  = (const float*)d_in[4];
    const float* eW = (const float*)d_in[5];
    const float* eb = (const float*)d_in[6];

    float* out  = (float*)d_out;
    float* hout = out;                                   // 50000*128
    float* att  = out + (size_t)N_NODES * HF;            // 800000*4

    char* wsb = (char*)d_ws;
    __hip_bfloat16* ht_bf = (__hip_bfloat16*)wsb;        // 12.8 MB
    float* alpha_i = (float*)(wsb + (size_t)N_NODES * HF * 2);
    float* alpha_j = alpha_i + N_NODES * HEADS;
    float* w_eff   = alpha_j + N_NODES * HEADS;
    float* b_eff   = w_eff + 128;
    unsigned short* W_T = (unsigned short*)(b_eff + 4);  // 16384 bf16 = 32 KB
    int*   deg     = (int*)(W_T + 128 * 128);            // 50,000 i
    int*   row_off = deg + N_NODES;                      // 50,001 i
    int*   blk_sums= row_off + N_NODES + 1;              // 196 i
    int*   blk_off = blk_sums + NBLK;                    // 196 i
    int*   rank    = (int*)((((uintptr_t)(blk_off + NBLK)) + 15) & ~(uintptr_t)15);
    uint4* rec     = (uint4*)((((uintptr_t)(rank + N_EDGES)) + 15) & ~(uintptr_t)15);
    float* rden_buf= (float*)(rec + N_EDGES);            // 200,000 f = 0.8 MB
    float4* nrec   = (float4*)(rden_buf + N_NODES * 4);  // 50,000 * 32B = 1.6 MB

    const int* row = ei;
    const int* col = ei + N_EDGES;

    (void)hipMemsetAsync(deg, 0, (size_t)N_NODES * sizeof(int), stream);

    prep_kernel<<<9, 256, 0, stream>>>(W, eW, eb, a, W_T, w_eff, b_eff);
    node_count_kernel<<<NODE_BLKS + CNT_BLKS, 256, 0, stream>>>(
        h, W_T, a, ht_bf, alpha_i, alpha_j, row, deg, rank);
    scan1_kernel<<<NBLK, SB, 0, stream>>>(deg, row_off, blk_sums);
    scan2_kernel<<<1, SB, 0, stream>>>(blk_sums, blk_off, row_off);
    scan3_kernel<<<NBLK, SB, 0, stream>>>(blk_off, row_off, alpha_i, nrec);
    edge_kernel<<<N_EDGES / 256, 256, 0, stream>>>(row, col, rank, ea, w_eff, b_eff,
                                                   nrec, alpha_j, rec, (float4*)att);
    agg_kernel<<<(N_NODES + 3) / 4, 256, 0, stream>>>(row_off, rec, ht_bf, hout, rden_buf);
    norm_kernel<<<N_EDGES / 256, 0 ? 0 : 256, 0, stream>>>(row, rden_buf, att);
}

// Round 9
// 314.323 us; speedup vs baseline: 1.3561x; 1.3561x over previous
//
#include <hip/hip_runtime.h>
#include <hip/hip_bf16.h>
#include <hip/hip_fp16.h>

#define N_NODES 50000
#define N_EDGES 800000
#define IN_F 128
#define OUT_F 32
#define HEADS 4
#define EDGE_F 32
#define HF 128          // HEADS*OUT_F
#define SB 256          // scan block size
#define NBLK ((N_NODES + SB - 1) / SB)   // 196 scan blocks
#define NODE_BLKS ((N_NODES + 63) / 64)  // 782
#define CNT_BLKS ((N_EDGES / 4 + 255) / 256)  // 782

typedef __attribute__((ext_vector_type(8))) short short8_t;  // 8 bf16 (4 VGPRs)
typedef __attribute__((ext_vector_type(4))) float f32x4;

__device__ __forceinline__ unsigned short f2bf(float x) {
    unsigned int u = __float_as_uint(x);
    unsigned int r = (u + 0x7FFF + ((u >> 16) & 1)) >> 16;   // RNE
    return (unsigned short)r;
}
__device__ __forceinline__ float bf2f(unsigned short b) {
    return __uint_as_float(((unsigned int)b) << 16);
}

// ---- fused prep: blocks 0-7 = W->bf16 transpose+swizzle; block 8 = w_eff/b_eff
__global__ __launch_bounds__(256) void prep_kernel(
        const float* __restrict__ W, const float* __restrict__ eW,
        const float* __restrict__ eb, const float* __restrict__ a,
        unsigned short* __restrict__ W_T,
        float* __restrict__ w_eff, float* __restrict__ b_eff) {
    int t = threadIdx.x;
    if (blockIdx.x < 8) {
        int g = blockIdx.x * 256 + t;            // 2048 = 128 n * 16 chunks
        int n = g >> 4, c = g & 15;
        unsigned short w8[8];
        #pragma unroll
        for (int q = 0; q < 8; ++q)
            w8[q] = f2bf(W[(size_t)(8 * c + q) * 128 + n]);
        *(uint4*)&W_T[n * 128 + ((c ^ (n & 7)) << 3)] = *(uint4*)w8;
    } else {
        if (t < 128) {
            int k = t >> 2, h = t & 3;
            float s = 0.f;
            #pragma unroll
            for (int f = 0; f < EDGE_F; ++f)
                s = fmaf(eW[k * HF + h * OUT_F + f], a[h * 96 + 2 * OUT_F + f], s);
            w_eff[k * 4 + h] = s;
        } else if (t < 132) {
            int h = t - 128;
            float s = 0.f;
            #pragma unroll
            for (int f = 0; f < EDGE_F; ++f)
                s = fmaf(eb[h * OUT_F + f], a[h * 96 + 2 * OUT_F + f], s);
            b_eff[h] = s;
        }
    }
}

// ---- grid-union: blocks [0,782) = MFMA node body; [782,1564) = count body
__global__ __launch_bounds__(256) void node_count_kernel(
        const float* __restrict__ h, const unsigned short* __restrict__ W_T,
        const float* __restrict__ a,
        __hip_bfloat16* __restrict__ ht_bf,
        float* __restrict__ alpha_i, float* __restrict__ alpha_j,
        const int* __restrict__ row, int* __restrict__ deg,
        int* __restrict__ rank) {
    __shared__ __align__(16) unsigned short Wl[128 * 128];   // 32 KB swizzled [n][k]
    __shared__ __align__(16) unsigned short Hhi[64 * 128];   // 16 KB swizzled [row][k]
    __shared__ __align__(16) unsigned short Hlo[64 * 128];   // 16 KB
    int t = threadIdx.x;
    if (blockIdx.x >= NODE_BLKS) {
        // ---------------- count body ----------------
        int i = (blockIdx.x - NODE_BLKS) * 256 + t;   // over N_EDGES/4
        if (i < N_EDGES / 4) {
            int4 r4 = ((const int4*)row)[i];
            int4 k4;
            k4.x = atomicAdd(&deg[r4.x], 1);
            k4.y = atomicAdd(&deg[r4.y], 1);
            k4.z = atomicAdd(&deg[r4.z], 1);
            k4.w = atomicAdd(&deg[r4.w], 1);
            ((int4*)rank)[i] = k4;                    // coalesced 16B write
        }
        return;
    }
    // ---------------- node body ----------------
    int lane = t & 63, wave = t >> 6;
    int nb = blockIdx.x * 64;
    {   // copy pre-swizzled W (32 KB): linear b128, even 8-way = floor
        const uint4* src = (const uint4*)W_T;
        uint4* dst = (uint4*)Wl;
        #pragma unroll
        for (int u = 0; u < 8; ++u) dst[t + u * 256] = src[t + u * 256];
    }
    // stage 64 h rows: coalesced float4 global, split hi/lo, swizzled LDS write
    #pragma unroll
    for (int u = 0; u < 8; ++u) {
        int f = u * 256 + t;
        int r_ = f >> 5, q = f & 31;             // q: float4 within row (k=4q..4q+3)
        int gn = nb + r_; if (gn > N_NODES - 1) gn = N_NODES - 1;
        float4 v = ((const float4*)h)[(size_t)gn * 32 + q];
        unsigned short hi[4], lo[4];
        #pragma unroll
        for (int x = 0; x < 4; ++x) {
            float xv = (&v.x)[x];
            unsigned short hb = f2bf(xv);
            hi[x] = hb;
            lo[x] = f2bf(xv - bf2f(hb));
        }
        int c = q >> 1, half = q & 1;
        int off = r_ * 128 + ((c ^ (r_ & 7)) << 3) + half * 4;
        *(uint2*)&Hhi[off] = *(uint2*)hi;
        *(uint2*)&Hlo[off] = *(uint2*)lo;
    }
    __syncthreads();
    int n0 = nb + wave * 16;
    if (n0 >= N_NODES) return;                   // tail block: waves 1-3 idle
    int r = lane & 15, g = lane >> 4;
    short8_t ahi[4], alo[4];
    #pragma unroll
    for (int k = 0; k < 4; ++k) {
        int c = k * 4 + g;
        int off = (wave * 16 + r) * 128 + ((c ^ (r & 7)) << 3);
        ahi[k] = *(const short8_t*)&Hhi[off];
        alo[k] = *(const short8_t*)&Hlo[off];
    }
    f32x4 acc[8];
    #pragma unroll
    for (int i = 0; i < 8; ++i) acc[i] = (f32x4){0.f, 0.f, 0.f, 0.f};
    #pragma unroll
    for (int tt = 0; tt < 8; ++tt) {             // 8 col-tiles of 16
        int n = tt * 16 + r;
        #pragma unroll
        for (int k = 0; k < 4; ++k) {
            int c = k * 4 + g;
            short8_t b = *(const short8_t*)&Wl[n * 128 + ((c ^ (n & 7)) << 3)];
            acc[tt] = __builtin_amdgcn_mfma_f32_16x16x32_bf16(ahi[k], b, acc[tt], 0, 0, 0);
            acc[tt] = __builtin_amdgcn_mfma_f32_16x16x32_bf16(alo[k], b, acc[tt], 0, 0, 0);
        }
    }
    // D layout: row = 4g + reg, col = 16tt + r
    #pragma unroll
    for (int tt = 0; tt < 8; ++tt)
        #pragma unroll
        for (int reg = 0; reg < 4; ++reg) {
            int rowg = n0 + 4 * g + reg;
            ((unsigned short*)ht_bf)[(size_t)rowg * 128 + tt * 16 + r] = f2bf(acc[tt][reg]);
        }
    float pi[4][4], pj[4][4];                    // [head][reg]
    #pragma unroll
    for (int hh = 0; hh < 4; ++hh) {
        float ai0 = a[hh * 96 + r],      ai1 = a[hh * 96 + 16 + r];
        float aj0 = a[hh * 96 + 32 + r], aj1 = a[hh * 96 + 48 + r];
        #pragma unroll
        for (int reg = 0; reg < 4; ++reg) {
            float v0 = acc[2 * hh][reg], v1 = acc[2 * hh + 1][reg];
            pi[hh][reg] = fmaf(v0, ai0, v1 * ai1);
            pj[hh][reg] = fmaf(v0, aj0, v1 * aj1);
        }
    }
    #pragma unroll
    for (int hh = 0; hh < 4; ++hh)
        #pragma unroll
        for (int reg = 0; reg < 4; ++reg) {
            float vi = pi[hh][reg], vj = pj[hh][reg];
            #pragma unroll
            for (int s = 1; s < 16; s <<= 1) {   // reduce over the 16 cols (lanes r)
                vi += __shfl_xor(vi, s, 64);
                vj += __shfl_xor(vj, s, 64);
            }
            pi[hh][reg] = vi; pj[hh][reg] = vj;
        }
    if (r == 0) {                                // 4 lanes/wave store 32 scalars each
        #pragma unroll
        for (int hh = 0; hh < 4; ++hh)
            #pragma unroll
            for (int reg = 0; reg < 4; ++reg) {
                int rowg = n0 + 4 * g + reg;
                alpha_i[rowg * 4 + hh] = pi[hh][reg];
                alpha_j[rowg * 4 + hh] = pj[hh][reg];
            }
    }
}

// ---- hierarchical exclusive scan ----------------------------------------
__device__ __forceinline__ int block_incl_scan(int v, int lane, int wid, int* wsum) {
    int x = v;
    #pragma unroll
    for (int s = 1; s < 64; s <<= 1) {
        int y = __shfl_up(x, s, 64);
        if (lane >= s) x += y;
    }
    if (lane == 63) wsum[wid] = x;
    __syncthreads();
    int add = 0;
    #pragma unroll
    for (int w = 0; w < 4; ++w) add += (w < wid) ? wsum[w] : 0;
    return x + add;            // block-level inclusive scan of v
}

__global__ __launch_bounds__(SB) void scan1_kernel(const int* __restrict__ deg,
                                                   int* __restrict__ row_off,
                                                   int* __restrict__ blk_sums) {
    __shared__ int wsum[4];
    int i = blockIdx.x * SB + threadIdx.x;
    int v = (i < N_NODES) ? deg[i] : 0;
    int incl = block_incl_scan(v, threadIdx.x & 63, threadIdx.x >> 6, wsum);
    if (i < N_NODES) row_off[i] = incl - v;              // local exclusive
    if (threadIdx.x == SB - 1) blk_sums[blockIdx.x] = incl;
}

__global__ __launch_bounds__(SB) void scan2_kernel(int* __restrict__ blk_sums,
                                                   int* __restrict__ blk_off,
                                                   int* __restrict__ row_off) {
    __shared__ int wsum[4];
    int t = threadIdx.x;
    int v = (t < NBLK) ? blk_sums[t] : 0;
    int incl = block_incl_scan(v, t & 63, t >> 6, wsum);
    if (t < NBLK) blk_off[t] = incl - v;                 // exclusive block offset
    if (t == SB - 1) row_off[N_NODES] = incl;            // grand total (== N_EDGES)
}

// scan3: finalize row_off AND build packed node record
// nrec[n] = 32B {alpha_i[0..3] fp32, row_off as-int, pad3} -> one gather line
__global__ __launch_bounds__(SB) void scan3_kernel(const int* __restrict__ blk_off,
                                                   int* __restrict__ row_off,
                                                   const float* __restrict__ alpha_i,
                                                   float4* __restrict__ nrec) {
    int i = blockIdx.x * SB + threadIdx.x;
    if (i < N_NODES) {
        int v = row_off[i] + blk_off[blockIdx.x];
        row_off[i] = v;
        float4 ai = *(const float4*)(alpha_i + (size_t)i * 4);
        nrec[(size_t)i * 2] = ai;
        float4 m;
        m.x = __int_as_float(v); m.y = 0.f; m.z = 0.f; m.w = 0.f;
        nrec[(size_t)i * 2 + 1] = m;
    }
}

// ---- unified edge kernel (R3 structure + nrec packed gather) ------------
__global__ __launch_bounds__(256) void edge_kernel(
        const int* __restrict__ row, const int* __restrict__ col,
        const int* __restrict__ rank,
        const float* __restrict__ ea,
        const float* __restrict__ w_eff, const float* __restrict__ b_eff,
        const float4* __restrict__ nrec, const float* __restrict__ alpha_j,
        uint4* __restrict__ rec, float4* __restrict__ att_ex) {
    __shared__ __align__(16) float eas[256 * 36];  // 36 KB, stride 36 floats
    __shared__ float wsd[128];
    __shared__ float bs[4];
    int t = threadIdx.x;
    if (t < 128) wsd[t] = w_eff[t];
    if (t < 4) bs[t] = b_eff[t];
    int e0 = blockIdx.x * 256;
    {   // coalesced stage: 2048 float4 = 256 edges x 128B
        const float4* src = (const float4*)ea + (size_t)e0 * 8;
        #pragma unroll
        for (int u = 0; u < 8; ++u) {
            int f = u * 256 + t;
            int el = f >> 3, j = f & 7;
            *(float4*)&eas[el * 36 + 4 * j] = src[f];
        }
    }
    __syncthreads();
    int e = e0 + t;
    float4 ev[8];
    #pragma unroll
    for (int i = 0; i < 8; ++i) ev[i] = *(const float4*)&eas[t * 36 + 4 * i];
    int r = row[e], c = col[e];
    int rk = rank[e];
    f32x4 ai = ((const f32x4*)nrec)[(size_t)r * 2];
    int ro = ((const int*)nrec)[(size_t)r * 8 + 4];   // same 32B line as ai
    f32x4 aj = *(const f32x4*)(alpha_j + (size_t)c * 4);
    float s0 = bs[0], s1 = bs[1], s2 = bs[2], s3 = bs[3];
    #pragma unroll
    for (int i = 0; i < 8; ++i) {
        #pragma unroll
        for (int kk = 0; kk < 4; ++kk) {
            float x = (&ev[i].x)[kk];
            float4 w4 = *(const float4*)&wsd[(i * 4 + kk) * 4];  // uniform -> broadcast
            s0 = fmaf(x, w4.x, s0);
            s1 = fmaf(x, w4.y, s1);
            s2 = fmaf(x, w4.z, s2);
            s3 = fmaf(x, w4.w, s3);
        }
    }
    float e0v = s0 + ai[0] + aj[0];
    float e1v = s1 + ai[1] + aj[1];
    float e2v = s2 + ai[2] + aj[2];
    float e3v = s3 + ai[3] + aj[3];
    e0v = e0v > 0.f ? e0v : 0.2f * e0v;           // leaky_relu(0.2)
    e1v = e1v > 0.f ? e1v : 0.2f * e1v;
    e2v = e2v > 0.f ? e2v : 0.2f * e2v;
    e3v = e3v > 0.f ? e3v : 0.2f * e3v;
    float x0 = __expf(e0v), x1 = __expf(e1v), x2 = __expf(e2v), x3 = __expf(e3v);
    att_ex[e] = make_float4(x0, x1, x2, x3);      // coalesced; normalized later
    __half2 p01 = __floats2half2_rn(x0, x1);
    __half2 p23 = __floats2half2_rn(x2, x3);
    uint4 o;
    o.x = *reinterpret_cast<unsigned int*>(&p01);
    o.y = *reinterpret_cast<unsigned int*>(&p23);
    o.z = (unsigned int)c;
    o.w = 0u;
    rec[ro + rk] = o;                             // single scattered 16B store
}

// ---- per-node aggregation: one wave per node, unroll-4 (named scalars) --
// R8 lesson: unroll-8 with rr[8]/hv[8] arrays spilled to scratch (642MB writes).
__global__ __launch_bounds__(256) void agg_kernel(
        const int* __restrict__ row_off, const uint4* __restrict__ rec,
        const __hip_bfloat16* __restrict__ ht_bf,
        float* __restrict__ hout, float* __restrict__ rden_buf) {
    int wave = threadIdx.x >> 6;
    int lane = threadIdx.x & 63;
    int n = blockIdx.x * 4 + wave;
    if (n >= N_NODES) return;
    int beg = row_off[n], end = row_off[n + 1];
    int h2 = lane >> 4;                            // head of cols 2L,2L+1
    int sh = (h2 & 1) * 16;                        // half-select within dword
    float2 acc0 = {0.f, 0.f}, acc1 = {0.f, 0.f};
    float den0 = 0.f, den1 = 0.f;
    int p = beg;
    for (; p + 3 < end; p += 4) {                  // unroll x4: 4 gathers in flight
        uint4 rA = rec[p];
        uint4 rB = rec[p + 1];
        uint4 rC = rec[p + 2];
        uint4 rD = rec[p + 3];
        unsigned int wA = (h2 & 2) ? rA.y : rA.x;
        unsigned int wB = (h2 & 2) ? rB.y : rB.x;
        unsigned int wC = (h2 & 2) ? rC.y : rC.x;
        unsigned int wD = (h2 & 2) ? rD.y : rD.x;
        float exA = __half2float(__ushort_as_half((unsigned short)(wA >> sh)));
        float exB = __half2float(__ushort_as_half((unsigned short)(wB >> sh)));
        float exC = __half2float(__ushort_as_half((unsigned short)(wC >> sh)));
        float exD = __half2float(__ushort_as_half((unsigned short)(wD >> sh)));
        float2 hvA = __bfloat1622float2(
            *(const __hip_bfloat162*)(ht_bf + (size_t)rA.z * HF + 2 * lane));
        float2 hvB = __bfloat1622float2(
            *(const __hip_bfloat162*)(ht_bf + (size_t)rB.z * HF + 2 * lane));
        float2 hvC = __bfloat1622float2(
            *(const __hip_bfloat162*)(ht_bf + (size_t)rC.z * HF + 2 * lane));
        float2 hvD = __bfloat1622float2(
            *(const __hip_bfloat162*)(ht_bf + (size_t)rD.z * HF + 2 * lane));
        acc0.x = fmaf(exA, hvA.x, acc0.x); acc0.y = fmaf(exA, hvA.y, acc0.y);
        acc1.x = fmaf(exB, hvB.x, acc1.x); acc1.y = fmaf(exB, hvB.y, acc1.y);
        acc0.x = fmaf(exC, hvC.x, acc0.x); acc0.y = fmaf(exC, hvC.y, acc0.y);
        acc1.x = fmaf(exD, hvD.x, acc1.x); acc1.y = fmaf(exD, hvD.y, acc1.y);
        den0 += exA + exC; den1 += exB + exD;
    }
    for (; p < end; ++p) {
        uint4 rA = rec[p];
        unsigned int wA = (h2 & 2) ? rA.y : rA.x;
        float exA = __half2float(__ushort_as_half((unsigned short)(wA >> sh)));
        float2 hvA = __bfloat1622float2(
            *(const __hip_bfloat162*)(ht_bf + (size_t)rA.z * HF + 2 * lane));
        acc0.x = fmaf(exA, hvA.x, acc0.x); acc0.y = fmaf(exA, hvA.y, acc0.y);
        den0 += exA;
    }
    float den = den0 + den1;
    float rden = 1.0f / (den + 1e-8f);
    float ox = (acc0.x + acc1.x) * rden, oy = (acc0.y + acc1.y) * rden;
    ox = ox > 0.f ? ox : expm1f(ox);               // fused ELU
    oy = oy > 0.f ? oy : expm1f(oy);
    float2 o = {ox, oy};
    ((float2*)(hout + (size_t)n * HF))[lane] = o;
    if ((lane & 15) == 0)                          // 4 lanes: rden per head, 16B line
        rden_buf[n * 4 + h2] = rden;
}

// ---- e-order att normalization: coalesced RMW + tiny rden gather --------
__global__ __launch_bounds__(256) void norm_kernel(const int* __restrict__ row,
                                                   const float* __restrict__ rden_buf,
                                                   float* __restrict__ att) {
    int e = blockIdx.x * 256 + threadIdx.x;        // 800000 = 3125*256 exact
    float4 ex = ((const float4*)att)[e];
    int r = row[e];
    float4 rd = *(const float4*)(rden_buf + (size_t)r * 4);
    ex.x *= rd.x; ex.y *= rd.y; ex.z *= rd.z; ex.w *= rd.w;
    ((float4*)att)[e] = ex;
}

extern "C" void kernel_launch(void* const* d_in, const int* in_sizes, int n_in,
                              void* d_out, int out_size, void* d_ws, size_t ws_size,
                              hipStream_t stream) {
    const float* h  = (const float*)d_in[0];
    const int*   ei = (const int*)  d_in[1];
    const float* ea = (const float*)d_in[2];
    const float* W  = (const float*)d_in[3];
    const float* a  = (const float*)d_in[4];
    const float* eW = (const float*)d_in[5];
    const float* eb = (const float*)d_in[6];

    float* out  = (float*)d_out;
    float* hout = out;                                   // 50000*128
    float* att  = out + (size_t)N_NODES * HF;            // 800000*4

    char* wsb = (char*)d_ws;
    __hip_bfloat16* ht_bf = (__hip_bfloat16*)wsb;        // 12.8 MB
    float* alpha_i = (float*)(wsb + (size_t)N_NODES * HF * 2);
    float* alpha_j = alpha_i + N_NODES * HEADS;
    float* w_eff   = alpha_j + N_NODES * HEADS;
    float* b_eff   = w_eff + 128;
    unsigned short* W_T = (unsigned short*)(b_eff + 4);  // 16384 bf16 = 32 KB
    int*   deg     = (int*)(W_T + 128 * 128);            // 50,000 i
    int*   row_off = deg + N_NODES;                      // 50,001 i
    int*   blk_sums= row_off + N_NODES + 1;              // 196 i
    int*   blk_off = blk_sums + NBLK;                    // 196 i
    int*   rank    = (int*)((((uintptr_t)(blk_off + NBLK)) + 15) & ~(uintptr_t)15);
    uint4* rec     = (uint4*)((((uintptr_t)(rank + N_EDGES)) + 15) & ~(uintptr_t)15);
    float* rden_buf= (float*)(rec + N_EDGES);            // 200,000 f = 0.8 MB
    float4* nrec   = (float4*)(rden_buf + N_NODES * 4);  // 50,000 * 32B = 1.6 MB

    const int* row = ei;
    const int* col = ei + N_EDGES;

    (void)hipMemsetAsync(deg, 0, (size_t)N_NODES * sizeof(int), stream);

    prep_kernel<<<9, 256, 0, stream>>>(W, eW, eb, a, W_T, w_eff, b_eff);
    node_count_kernel<<<NODE_BLKS + CNT_BLKS, 256, 0, stream>>>(
        h, W_T, a, ht_bf, alpha_i, alpha_j, row, deg, rank);
    scan1_kernel<<<NBLK, SB, 0, stream>>>(deg, row_off, blk_sums);
    scan2_kernel<<<1, SB, 0, stream>>>(blk_sums, blk_off, row_off);
    scan3_kernel<<<NBLK, SB, 0, stream>>>(blk_off, row_off, alpha_i, nrec);
    edge_kernel<<<N_EDGES / 256, 256, 0, stream>>>(row, col, rank, ea, w_eff, b_eff,
                                                   nrec, alpha_j, rec, (float4*)att);
    agg_kernel<<<(N_NODES + 3) / 4, 256, 0, stream>>>(row_off, rec, ht_bf, hout, rden_buf);
    norm_kernel<<<N_EDGES / 256, 256, 0, stream>>>(row, rden_buf, att);
}

// Round 10
// 313.316 us; speedup vs baseline: 1.3605x; 1.0032x over previous
//
#include <hip/hip_runtime.h>
#include <hip/hip_bf16.h>
#include <hip/hip_fp16.h>

#define N_NODES 50000
#define N_EDGES 800000
#define IN_F 128
#define OUT_F 32
#define HEADS 4
#define EDGE_F 32
#define HF 128          // HEADS*OUT_F
#define SB 256          // scan block size
#define NBLK ((N_NODES + SB - 1) / SB)   // 196 scan blocks
#define NODE_BLKS ((N_NODES + 63) / 64)  // 782
#define CNT_BLKS ((N_EDGES / 4 + 255) / 256)  // 782

typedef __attribute__((ext_vector_type(8))) short short8_t;  // 8 bf16 (4 VGPRs)
typedef __attribute__((ext_vector_type(4))) float f32x4;

__device__ __forceinline__ unsigned short f2bf(float x) {
    unsigned int u = __float_as_uint(x);
    unsigned int r = (u + 0x7FFF + ((u >> 16) & 1)) >> 16;   // RNE
    return (unsigned short)r;
}
__device__ __forceinline__ float bf2f(unsigned short b) {
    return __uint_as_float(((unsigned int)b) << 16);
}

// ---- fused prep: blocks 0-7 = W->bf16 transpose+swizzle; block 8 = w_eff/b_eff
__global__ __launch_bounds__(256) void prep_kernel(
        const float* __restrict__ W, const float* __restrict__ eW,
        const float* __restrict__ eb, const float* __restrict__ a,
        unsigned short* __restrict__ W_T,
        float* __restrict__ w_eff, float* __restrict__ b_eff) {
    int t = threadIdx.x;
    if (blockIdx.x < 8) {
        int g = blockIdx.x * 256 + t;            // 2048 = 128 n * 16 chunks
        int n = g >> 4, c = g & 15;
        unsigned short w8[8];
        #pragma unroll
        for (int q = 0; q < 8; ++q)
            w8[q] = f2bf(W[(size_t)(8 * c + q) * 128 + n]);
        *(uint4*)&W_T[n * 128 + ((c ^ (n & 7)) << 3)] = *(uint4*)w8;
    } else {
        if (t < 128) {
            int k = t >> 2, h = t & 3;
            float s = 0.f;
            #pragma unroll
            for (int f = 0; f < EDGE_F; ++f)
                s = fmaf(eW[k * HF + h * OUT_F + f], a[h * 96 + 2 * OUT_F + f], s);
            w_eff[k * 4 + h] = s;
        } else if (t < 132) {
            int h = t - 128;
            float s = 0.f;
            #pragma unroll
            for (int f = 0; f < EDGE_F; ++f)
                s = fmaf(eb[h * OUT_F + f], a[h * 96 + 2 * OUT_F + f], s);
            b_eff[h] = s;
        }
    }
}

// ---- grid-union: blocks [0,782) = MFMA node body; [782,1564) = count body
// R9: Wl LDS staging dropped -> B-frags read from L1/L2-resident W_T (32KB hot).
// LDS 64KB->32KB: 2 -> 5 blocks/CU.
__global__ __launch_bounds__(256) void node_count_kernel(
        const float* __restrict__ h, const unsigned short* __restrict__ W_T,
        const float* __restrict__ a,
        __hip_bfloat16* __restrict__ ht_bf,
        float* __restrict__ alpha_i, float* __restrict__ alpha_j,
        const int* __restrict__ row, int* __restrict__ deg,
        int* __restrict__ rank) {
    __shared__ __align__(16) unsigned short Hhi[64 * 128];   // 16 KB swizzled [row][k]
    __shared__ __align__(16) unsigned short Hlo[64 * 128];   // 16 KB
    int t = threadIdx.x;
    if (blockIdx.x >= NODE_BLKS) {
        // ---------------- count body ----------------
        int i = (blockIdx.x - NODE_BLKS) * 256 + t;   // over N_EDGES/4
        if (i < N_EDGES / 4) {
            int4 r4 = ((const int4*)row)[i];
            int4 k4;
            k4.x = atomicAdd(&deg[r4.x], 1);
            k4.y = atomicAdd(&deg[r4.y], 1);
            k4.z = atomicAdd(&deg[r4.z], 1);
            k4.w = atomicAdd(&deg[r4.w], 1);
            ((int4*)rank)[i] = k4;                    // coalesced 16B write
        }
        return;
    }
    // ---------------- node body ----------------
    int lane = t & 63, wave = t >> 6;
    int nb = blockIdx.x * 64;
    // stage 64 h rows: coalesced float4 global, split hi/lo, swizzled LDS write
    #pragma unroll
    for (int u = 0; u < 8; ++u) {
        int f = u * 256 + t;
        int r_ = f >> 5, q = f & 31;             // q: float4 within row (k=4q..4q+3)
        int gn = nb + r_; if (gn > N_NODES - 1) gn = N_NODES - 1;
        float4 v = ((const float4*)h)[(size_t)gn * 32 + q];
        unsigned short hi[4], lo[4];
        #pragma unroll
        for (int x = 0; x < 4; ++x) {
            float xv = (&v.x)[x];
            unsigned short hb = f2bf(xv);
            hi[x] = hb;
            lo[x] = f2bf(xv - bf2f(hb));
        }
        int c = q >> 1, half = q & 1;
        int off = r_ * 128 + ((c ^ (r_ & 7)) << 3) + half * 4;
        *(uint2*)&Hhi[off] = *(uint2*)hi;
        *(uint2*)&Hlo[off] = *(uint2*)lo;
    }
    __syncthreads();
    int n0 = nb + wave * 16;
    if (n0 >= N_NODES) return;                   // tail block: waves 1-3 idle
    int r = lane & 15, g = lane >> 4;
    short8_t ahi[4], alo[4];
    #pragma unroll
    for (int k = 0; k < 4; ++k) {
        int c = k * 4 + g;
        int off = (wave * 16 + r) * 128 + ((c ^ (r & 7)) << 3);
        ahi[k] = *(const short8_t*)&Hhi[off];
        alo[k] = *(const short8_t*)&Hlo[off];
    }
    f32x4 acc[8];
    #pragma unroll
    for (int i = 0; i < 8; ++i) acc[i] = (f32x4){0.f, 0.f, 0.f, 0.f};
    #pragma unroll
    for (int tt = 0; tt < 8; ++tt) {             // 8 col-tiles of 16
        int n = tt * 16 + r;
        #pragma unroll
        for (int k = 0; k < 4; ++k) {
            int c = k * 4 + g;
            // direct global read: W_T is 32KB, L1-resident after first touch
            short8_t b = *(const short8_t*)&W_T[n * 128 + ((c ^ (n & 7)) << 3)];
            acc[tt] = __builtin_amdgcn_mfma_f32_16x16x32_bf16(ahi[k], b, acc[tt], 0, 0, 0);
            acc[tt] = __builtin_amdgcn_mfma_f32_16x16x32_bf16(alo[k], b, acc[tt], 0, 0, 0);
        }
    }
    // D layout: row = 4g + reg, col = 16tt + r
    #pragma unroll
    for (int tt = 0; tt < 8; ++tt)
        #pragma unroll
        for (int reg = 0; reg < 4; ++reg) {
            int rowg = n0 + 4 * g + reg;
            ((unsigned short*)ht_bf)[(size_t)rowg * 128 + tt * 16 + r] = f2bf(acc[tt][reg]);
        }
    float pi[4][4], pj[4][4];                    // [head][reg]
    #pragma unroll
    for (int hh = 0; hh < 4; ++hh) {
        float ai0 = a[hh * 96 + r],      ai1 = a[hh * 96 + 16 + r];
        float aj0 = a[hh * 96 + 32 + r], aj1 = a[hh * 96 + 48 + r];
        #pragma unroll
        for (int reg = 0; reg < 4; ++reg) {
            float v0 = acc[2 * hh][reg], v1 = acc[2 * hh + 1][reg];
            pi[hh][reg] = fmaf(v0, ai0, v1 * ai1);
            pj[hh][reg] = fmaf(v0, aj0, v1 * aj1);
        }
    }
    #pragma unroll
    for (int hh = 0; hh < 4; ++hh)
        #pragma unroll
        for (int reg = 0; reg < 4; ++reg) {
            float vi = pi[hh][reg], vj = pj[hh][reg];
            #pragma unroll
            for (int s = 1; s < 16; s <<= 1) {   // reduce over the 16 cols (lanes r)
                vi += __shfl_xor(vi, s, 64);
                vj += __shfl_xor(vj, s, 64);
            }
            pi[hh][reg] = vi; pj[hh][reg] = vj;
        }
    if (r == 0) {                                // 4 lanes/wave store 32 scalars each
        #pragma unroll
        for (int hh = 0; hh < 4; ++hh)
            #pragma unroll
            for (int reg = 0; reg < 4; ++reg) {
                int rowg = n0 + 4 * g + reg;
                alpha_i[rowg * 4 + hh] = pi[hh][reg];
                alpha_j[rowg * 4 + hh] = pj[hh][reg];
            }
    }
}

// ---- hierarchical exclusive scan ----------------------------------------
__device__ __forceinline__ int block_incl_scan(int v, int lane, int wid, int* wsum) {
    int x = v;
    #pragma unroll
    for (int s = 1; s < 64; s <<= 1) {
        int y = __shfl_up(x, s, 64);
        if (lane >= s) x += y;
    }
    if (lane == 63) wsum[wid] = x;
    __syncthreads();
    int add = 0;
    #pragma unroll
    for (int w = 0; w < 4; ++w) add += (w < wid) ? wsum[w] : 0;
    return x + add;            // block-level inclusive scan of v
}

__global__ __launch_bounds__(SB) void scan1_kernel(const int* __restrict__ deg,
                                                   int* __restrict__ row_off,
                                                   int* __restrict__ blk_sums) {
    __shared__ int wsum[4];
    int i = blockIdx.x * SB + threadIdx.x;
    int v = (i < N_NODES) ? deg[i] : 0;
    int incl = block_incl_scan(v, threadIdx.x & 63, threadIdx.x >> 6, wsum);
    if (i < N_NODES) row_off[i] = incl - v;              // local exclusive
    if (threadIdx.x == SB - 1) blk_sums[blockIdx.x] = incl;
}

__global__ __launch_bounds__(SB) void scan2_kernel(int* __restrict__ blk_sums,
                                                   int* __restrict__ blk_off,
                                                   int* __restrict__ row_off) {
    __shared__ int wsum[4];
    int t = threadIdx.x;
    int v = (t < NBLK) ? blk_sums[t] : 0;
    int incl = block_incl_scan(v, t & 63, t >> 6, wsum);
    if (t < NBLK) blk_off[t] = incl - v;                 // exclusive block offset
    if (t == SB - 1) row_off[N_NODES] = incl;            // grand total (== N_EDGES)
}

// scan3: finalize row_off AND build packed node record
// nrec[n] = 32B {alpha_i[0..3] fp32, row_off as-int, pad3} -> one gather line
__global__ __launch_bounds__(SB) void scan3_kernel(const int* __restrict__ blk_off,
                                                   int* __restrict__ row_off,
                                                   const float* __restrict__ alpha_i,
                                                   float4* __restrict__ nrec) {
    int i = blockIdx.x * SB + threadIdx.x;
    if (i < N_NODES) {
        int v = row_off[i] + blk_off[blockIdx.x];
        row_off[i] = v;
        float4 ai = *(const float4*)(alpha_i + (size_t)i * 4);
        nrec[(size_t)i * 2] = ai;
        float4 m;
        m.x = __int_as_float(v); m.y = 0.f; m.z = 0.f; m.w = 0.f;
        nrec[(size_t)i * 2 + 1] = m;
    }
}

// ---- unified edge kernel (R3 structure + nrec packed gather) ------------
__global__ __launch_bounds__(256) void edge_kernel(
        const int* __restrict__ row, const int* __restrict__ col,
        const int* __restrict__ rank,
        const float* __restrict__ ea,
        const float* __restrict__ w_eff, const float* __restrict__ b_eff,
        const float4* __restrict__ nrec, const float* __restrict__ alpha_j,
        uint4* __restrict__ rec, float4* __restrict__ att_ex) {
    __shared__ __align__(16) float eas[256 * 36];  // 36 KB, stride 36 floats
    __shared__ float wsd[128];
    __shared__ float bs[4];
    int t = threadIdx.x;
    if (t < 128) wsd[t] = w_eff[t];
    if (t < 4) bs[t] = b_eff[t];
    int e0 = blockIdx.x * 256;
    {   // coalesced stage: 2048 float4 = 256 edges x 128B
        const float4* src = (const float4*)ea + (size_t)e0 * 8;
        #pragma unroll
        for (int u = 0; u < 8; ++u) {
            int f = u * 256 + t;
            int el = f >> 3, j = f & 7;
            *(float4*)&eas[el * 36 + 4 * j] = src[f];
        }
    }
    __syncthreads();
    int e = e0 + t;
    float4 ev[8];
    #pragma unroll
    for (int i = 0; i < 8; ++i) ev[i] = *(const float4*)&eas[t * 36 + 4 * i];
    int r = row[e], c = col[e];
    int rk = rank[e];
    f32x4 ai = ((const f32x4*)nrec)[(size_t)r * 2];
    int ro = ((const int*)nrec)[(size_t)r * 8 + 4];   // same 32B line as ai
    f32x4 aj = *(const f32x4*)(alpha_j + (size_t)c * 4);
    float s0 = bs[0], s1 = bs[1], s2 = bs[2], s3 = bs[3];
    #pragma unroll
    for (int i = 0; i < 8; ++i) {
        #pragma unroll
        for (int kk = 0; kk < 4; ++kk) {
            float x = (&ev[i].x)[kk];
            float4 w4 = *(const float4*)&wsd[(i * 4 + kk) * 4];  // uniform -> broadcast
            s0 = fmaf(x, w4.x, s0);
            s1 = fmaf(x, w4.y, s1);
            s2 = fmaf(x, w4.z, s2);
            s3 = fmaf(x, w4.w, s3);
        }
    }
    float e0v = s0 + ai[0] + aj[0];
    float e1v = s1 + ai[1] + aj[1];
    float e2v = s2 + ai[2] + aj[2];
    float e3v = s3 + ai[3] + aj[3];
    e0v = e0v > 0.f ? e0v : 0.2f * e0v;           // leaky_relu(0.2)
    e1v = e1v > 0.f ? e1v : 0.2f * e1v;
    e2v = e2v > 0.f ? e2v : 0.2f * e2v;
    e3v = e3v > 0.f ? e3v : 0.2f * e3v;
    float x0 = __expf(e0v), x1 = __expf(e1v), x2 = __expf(e2v), x3 = __expf(e3v);
    att_ex[e] = make_float4(x0, x1, x2, x3);      // coalesced; normalized later
    __half2 p01 = __floats2half2_rn(x0, x1);
    __half2 p23 = __floats2half2_rn(x2, x3);
    uint4 o;
    o.x = *reinterpret_cast<unsigned int*>(&p01);
    o.y = *reinterpret_cast<unsigned int*>(&p23);
    o.z = (unsigned int)c;
    o.w = 0u;
    rec[ro + rk] = o;                             // single scattered 16B store
}

// ---- per-node aggregation: one wave per node, unroll-4 (named scalars) --
__global__ __launch_bounds__(256) void agg_kernel(
        const int* __restrict__ row_off, const uint4* __restrict__ rec,
        const __hip_bfloat16* __restrict__ ht_bf,
        float* __restrict__ hout, float* __restrict__ rden_buf) {
    int wave = threadIdx.x >> 6;
    int lane = threadIdx.x & 63;
    int n = blockIdx.x * 4 + wave;
    if (n >= N_NODES) return;
    int beg = row_off[n], end = row_off[n + 1];
    int h2 = lane >> 4;                            // head of cols 2L,2L+1
    int sh = (h2 & 1) * 16;                        // half-select within dword
    float2 acc0 = {0.f, 0.f}, acc1 = {0.f, 0.f};
    float den0 = 0.f, den1 = 0.f;
    int p = beg;
    for (; p + 3 < end; p += 4) {                  // unroll x4: 4 gathers in flight
        uint4 rA = rec[p];
        uint4 rB = rec[p + 1];
        uint4 rC = rec[p + 2];
        uint4 rD = rec[p + 3];
        unsigned int wA = (h2 & 2) ? rA.y : rA.x;
        unsigned int wB = (h2 & 2) ? rB.y : rB.x;
        unsigned int wC = (h2 & 2) ? rC.y : rC.x;
        unsigned int wD = (h2 & 2) ? rD.y : rD.x;
        float exA = __half2float(__ushort_as_half((unsigned short)(wA >> sh)));
        float exB = __half2float(__ushort_as_half((unsigned short)(wB >> sh)));
        float exC = __half2float(__ushort_as_half((unsigned short)(wC >> sh)));
        float exD = __half2float(__ushort_as_half((unsigned short)(wD >> sh)));
        float2 hvA = __bfloat1622float2(
            *(const __hip_bfloat162*)(ht_bf + (size_t)rA.z * HF + 2 * lane));
        float2 hvB = __bfloat1622float2(
            *(const __hip_bfloat162*)(ht_bf + (size_t)rB.z * HF + 2 * lane));
        float2 hvC = __bfloat1622float2(
            *(const __hip_bfloat162*)(ht_bf + (size_t)rC.z * HF + 2 * lane));
        float2 hvD = __bfloat1622float2(
            *(const __hip_bfloat162*)(ht_bf + (size_t)rD.z * HF + 2 * lane));
        acc0.x = fmaf(exA, hvA.x, acc0.x); acc0.y = fmaf(exA, hvA.y, acc0.y);
        acc1.x = fmaf(exB, hvB.x, acc1.x); acc1.y = fmaf(exB, hvB.y, acc1.y);
        acc0.x = fmaf(exC, hvC.x, acc0.x); acc0.y = fmaf(exC, hvC.y, acc0.y);
        acc1.x = fmaf(exD, hvD.x, acc1.x); acc1.y = fmaf(exD, hvD.y, acc1.y);
        den0 += exA + exC; den1 += exB + exD;
    }
    for (; p < end; ++p) {
        uint4 rA = rec[p];
        unsigned int wA = (h2 & 2) ? rA.y : rA.x;
        float exA = __half2float(__ushort_as_half((unsigned short)(wA >> sh)));
        float2 hvA = __bfloat1622float2(
            *(const __hip_bfloat162*)(ht_bf + (size_t)rA.z * HF + 2 * lane));
        acc0.x = fmaf(exA, hvA.x, acc0.x); acc0.y = fmaf(exA, hvA.y, acc0.y);
        den0 += exA;
    }
    float den = den0 + den1;
    float rden = 1.0f / (den + 1e-8f);
    float ox = (acc0.x + acc1.x) * rden, oy = (acc0.y + acc1.y) * rden;
    ox = ox > 0.f ? ox : expm1f(ox);               // fused ELU
    oy = oy > 0.f ? oy : expm1f(oy);
    float2 o = {ox, oy};
    ((float2*)(hout + (size_t)n * HF))[lane] = o;
    if ((lane & 15) == 0)                          // 4 lanes: rden per head, 16B line
        rden_buf[n * 4 + h2] = rden;
}

// ---- e-order att normalization: coalesced RMW + tiny rden gather --------
__global__ __launch_bounds__(256) void norm_kernel(const int* __restrict__ row,
                                                   const float* __restrict__ rden_buf,
                                                   float* __restrict__ att) {
    int e = blockIdx.x * 256 + threadIdx.x;        // 800000 = 3125*256 exact
    float4 ex = ((const float4*)att)[e];
    int r = row[e];
    float4 rd = *(const float4*)(rden_buf + (size_t)r * 4);
    ex.x *= rd.x; ex.y *= rd.y; ex.z *= rd.z; ex.w *= rd.w;
    ((float4*)att)[e] = ex;
}

extern "C" void kernel_launch(void* const* d_in, const int* in_sizes, int n_in,
                              void* d_out, int out_size, void* d_ws, size_t ws_size,
                              hipStream_t stream) {
    const float* h  = (const float*)d_in[0];
    const int*   ei = (const int*)  d_in[1];
    const float* ea = (const float*)d_in[2];
    const float* W  = (const float*)d_in[3];
    const float* a  = (const float*)d_in[4];
    const float* eW = (const float*)d_in[5];
    const float* eb = (const float*)d_in[6];

    float* out  = (float*)d_out;
    float* hout = out;                                   // 50000*128
    float* att  = out + (size_t)N_NODES * HF;            // 800000*4

    char* wsb = (char*)d_ws;
    __hip_bfloat16* ht_bf = (__hip_bfloat16*)wsb;        // 12.8 MB
    float* alpha_i = (float*)(wsb + (size_t)N_NODES * HF * 2);
    float* alpha_j = alpha_i + N_NODES * HEADS;
    float* w_eff   = alpha_j + N_NODES * HEADS;
    float* b_eff   = w_eff + 128;
    unsigned short* W_T = (unsigned short*)(b_eff + 4);  // 16384 bf16 = 32 KB
    int*   deg     = (int*)(W_T + 128 * 128);            // 50,000 i
    int*   row_off = deg + N_NODES;                      // 50,001 i
    int*   blk_sums= row_off + N_NODES + 1;              // 196 i
    int*   blk_off = blk_sums + NBLK;                    // 196 i
    int*   rank    = (int*)((((uintptr_t)(blk_off + NBLK)) + 15) & ~(uintptr_t)15);
    uint4* rec     = (uint4*)((((uintptr_t)(rank + N_EDGES)) + 15) & ~(uintptr_t)15);
    float* rden_buf= (float*)(rec + N_EDGES);            // 200,000 f = 0.8 MB
    float4* nrec   = (float4*)(rden_buf + N_NODES * 4);  // 50,000 * 32B = 1.6 MB

    const int* row = ei;
    const int* col = ei + N_EDGES;

    (void)hipMemsetAsync(deg, 0, (size_t)N_NODES * sizeof(int), stream);

    prep_kernel<<<9, 256, 0, stream>>>(W, eW, eb, a, W_T, w_eff, b_eff);
    node_count_kernel<<<NODE_BLKS + CNT_BLKS, 256, 0, stream>>>(
        h, W_T, a, ht_bf, alpha_i, alpha_j, row, deg, rank);
    scan1_kernel<<<NBLK, SB, 0, stream>>>(deg, row_off, blk_sums);
    scan2_kernel<<<1, SB, 0, stream>>>(blk_sums, blk_off, row_off);
    scan3_kernel<<<NBLK, SB, 0, stream>>>(blk_off, row_off, alpha_i, nrec);
    edge_kernel<<<N_EDGES / 256, 256, 0, stream>>>(row, col, rank, ea, w_eff, b_eff,
                                                   nrec, alpha_j, rec, (float4*)att);
    agg_kernel<<<(N_NODES + 3) / 4, 256, 0, stream>>>(row_off, rec, ht_bf, hout, rden_buf);
    norm_kernel<<<N_EDGES / 256, 256, 0, stream>>>(row, rden_buf, att);
}